// Round 14
// baseline (155.232 us; speedup 1.0000x reference)
//
#include <hip/hip_runtime.h>
#include <math.h>

#define NN 50000
#define NE 800000
#define BINW 256
#define NB ((NN + BINW - 1) / BINW)   // 196 buckets
#define CAP 4864                      // per-bucket capacity (mean 4082, sd ~64)
#define CHUNK 4096
#define NBIN ((NE + CHUNK - 1) / CHUNK)   // 196 bin blocks
#define NXB 6250                      // x-convert blocks
#define NWB 256                       // weight-convert blocks
#define EPT 16                        // edges per thread in bin phase

typedef __attribute__((ext_vector_type(8))) _Float16 f16x8;
typedef __attribute__((ext_vector_type(2))) _Float16 h2;
typedef __attribute__((ext_vector_type(4))) float f32x4;
typedef unsigned int uint32;
typedef __attribute__((address_space(3))) unsigned int lds_uint;
typedef const __attribute__((address_space(1))) unsigned int glb_uint;

__device__ inline unsigned short f2h(float f) {
    _Float16 h = (_Float16)f;        // v_cvt_f16_f32 (RNE)
    return __builtin_bit_cast(unsigned short, h);
}
__device__ inline uint32 pack2h(float a, float b) {
    return (uint32)f2h(a) | ((uint32)f2h(b) << 16);
}
__device__ inline h2 as_h2(uint32 u) { return __builtin_bit_cast(h2, u); }

// fp32 -> e4m3 byte (RNE, via fp16; denormals handled; clamp at +-448)
__device__ inline uint32 f2e4m3(float f) {
    unsigned short h = f2h(f);
    uint32 s = (h >> 8) & 0x80u;
    int E = (h >> 10) & 0x1F;
    int M = h & 0x3FF;
    if (E >= 24) return s | 0x7Eu;
    if (E > 8) {
        int m = M >> 7, r = M & 0x7F;
        if (r > 0x40 || (r == 0x40 && (m & 1))) { m++; if (m == 8) { m = 0; E++; if (E >= 24) return s | 0x7Eu; } }
        return s | (uint32)((E - 8) << 3) | (uint32)m;
    }
    if (E < 5) return s;                  // underflow -> 0
    int sh = 16 - E;                      // 8..11
    int t = 1024 + M;
    int m = t >> sh;
    int rem = t & ((1 << sh) - 1);
    int half = 1 << (sh - 1);
    if (rem > half || (rem == half && (m & 1))) m++;
    if (m >= 8) return s | 0x08u;         // rounds up to 2^-6
    return s | (uint32)m;
}

// decode 4 e4m3 bytes (one word) into two packed-fp16 words and accumulate.
// normals exact; zeros/denormals decode with <=0.008 abs error (negligible
// after mean-aggregation; analyzed in journal).
__device__ inline void dec_acc(uint32 w, h2* a) {
    uint32 u01 = (w & 0x7Fu) | ((w & 0x7F00u) << 8);
    uint32 u23 = ((w >> 16) & 0x7Fu) | ((w >> 8) & 0x7F0000u);
    uint32 h01 = ((u01 << 7) + 0x20002000u) | ((w & 0x80u) << 8) | ((w & 0x8000u) << 16);
    uint32 h23 = ((u23 << 7) + 0x20002000u) | ((w >> 8) & 0x8000u) | (w & 0x80000000u);
    a[0] += as_h2(h01);
    a[1] += as_h2(h23);
}
#define ACC8Q(vv) { dec_acc((vv).x, a); dec_acc((vv).y, a + 2); }

__device__ inline int edge_at(const void* edges, int is64, int i) {
    return is64 ? (int)((const long long*)edges)[i] : ((const int*)edges)[i];
}

// ---------------------------------------------------------------------------
// k_front: one launch, no cross-block deps:
// blocks [0,NBIN): bin CHUNK edges by bucket=dst>>8 -> bucket-major gbuf
// blocks [NBIN, NBIN+NXB): x fp32 -> fp16 into A1 cols 128:256 AND fp8 x8
// blocks [NBIN+NXB, ..+NWB): weights -> n-major fp16 tables
// ---------------------------------------------------------------------------
__global__ __launch_bounds__(256)
void k_front(const void* __restrict__ edges, uint32* __restrict__ gbuf,
             int* __restrict__ bcnt,
             const float* __restrict__ x, unsigned short* __restrict__ A1,
             uint32* __restrict__ x8w,
             const float* __restrict__ W1l, const float* __restrict__ W1r,
             const float* __restrict__ W2l, const float* __restrict__ W2r,
             unsigned short* __restrict__ B1t, unsigned short* __restrict__ B2t) {
    int b = blockIdx.x;
    if (b >= NBIN) {
        if (b < NBIN + NXB) {
            int t = (b - NBIN) * 256 + threadIdx.x;
            if (t >= NN * 32) return;
            int node = t >> 5, q = t & 31;
            float4 v = *(const float4*)(x + (size_t)node * 128 + q * 4);
            *(uint2*)(A1 + (size_t)node * 256 + 128 + q * 4) =
                make_uint2(pack2h(v.x, v.y), pack2h(v.z, v.w));
            x8w[(size_t)node * 32 + q] = f2e4m3(v.x) | (f2e4m3(v.y) << 8) |
                                         (f2e4m3(v.z) << 16) | (f2e4m3(v.w) << 24);
        } else {
            int t = (b - NBIN - NXB) * 256 + threadIdx.x;
            int n = t >> 8, k = t & 255;
            float v1 = (k < 128) ? W1l[k * 256 + n] : W1r[(k - 128) * 256 + n];
            B1t[n * 256 + k] = f2h(v1);
            float v2 = (n < 128) ? W2l[k * 128 + n] : W2r[k * 128 + (n - 128)];
            B2t[n * 256 + k] = f2h(v2);
        }
        return;
    }
    // ---- bin block
    __shared__ int hist[NB], excl[NB], cur[NB], gpos[NB];
    __shared__ int is64s;
    __shared__ uint32 sorted[CHUNK];
    int t = threadIdx.x;
    int base = b * CHUNK;
    int n = NE - base; if (n > CHUNK) n = CHUNK;
    if (t < 64) {
        const long long* q = (const long long*)edges;
        long long v = q[t];
        unsigned long long m = __ballot(v >= 0 && v < NN);
        if (t == 0) is64s = (m == ~0ull) ? 1 : 0;
    }
    for (int i = t; i < NB; i += 256) hist[i] = 0;
    __syncthreads();
    int is64 = is64s;
    int sA[EPT], dA[EPT];
    #pragma unroll
    for (int q = 0; q < EPT; ++q) {
        int i = t + q * 256;
        if (i < n) {
            sA[q] = edge_at(edges, is64, base + i);
            dA[q] = edge_at(edges, is64, NE + base + i);
        } else dA[q] = -1;
    }
    #pragma unroll
    for (int q = 0; q < EPT; ++q)
        if (dA[q] >= 0) atomicAdd(&hist[dA[q] >> 8], 1);
    __syncthreads();
    if (t == 0) {
        int s = 0;
        for (int k = 0; k < NB; ++k) { excl[k] = s; s += hist[k]; }
    }
    __syncthreads();
    for (int i = t; i < NB; i += 256) {
        gpos[i] = atomicAdd(&bcnt[i], hist[i]);
        cur[i] = excl[i];
    }
    __syncthreads();
    // local bucket-sort into LDS, bucket id packed in bits 24+
    #pragma unroll
    for (int q = 0; q < EPT; ++q) {
        if (dA[q] >= 0) {
            int bk = dA[q] >> 8;
            int lp = atomicAdd(&cur[bk], 1);
            sorted[lp] = ((uint32)bk << 24) | ((uint32)(dA[q] & (BINW - 1)) << 16) | (uint32)sA[q];
        }
    }
    __syncthreads();
    // coalesced-run write to bucket-major gbuf (no binary search)
    for (int i = t; i < n; i += 256) {
        uint32 v = sorted[i];
        int bk = v >> 24;
        int gp = gpos[bk] + (i - excl[bk]);
        if (gp < CAP) gbuf[(size_t)bk * CAP + gp] = v & 0xFFFFFFu;
    }
}

// ---------------------------------------------------------------------------
// k_sort: one block per bucket -> offs[] + dst-sorted src list (uint16)
// ---------------------------------------------------------------------------
__global__ __launch_bounds__(256) void k_sort(const uint32* __restrict__ gbuf,
                                              const int* __restrict__ bcnt,
                                              int* __restrict__ offs,
                                              unsigned short* __restrict__ ssrc) {
    __shared__ int hist[BINW], cur[BINW], wsum[4];
    __shared__ int sorted[CAP];
    __shared__ int bb_s;
    int b = blockIdx.x, t = threadIdx.x;
    int lane = t & 63, w = t >> 6;
    int c = (t < NB) ? bcnt[t] : 0;
    int pre = (t < b) ? c : 0;
    #pragma unroll
    for (int s = 1; s < 64; s <<= 1) pre += __shfl_xor(pre, s);
    if (lane == 0) wsum[w] = pre;
    hist[t] = 0;
    __syncthreads();
    if (t == 0) bb_s = wsum[0] + wsum[1] + wsum[2] + wsum[3];
    __syncthreads();
    int bb = bb_s;
    int cnt = bcnt[b]; if (cnt > CAP) cnt = CAP;
    int nbase = b * BINW;
    int ncnt = NN - nbase; if (ncnt > BINW) ncnt = BINW;
    for (int i = t; i < cnt; i += 256)
        atomicAdd(&hist[gbuf[(size_t)b * CAP + i] >> 16], 1);
    __syncthreads();
    int d = hist[t];
    int v = d;
    #pragma unroll
    for (int s = 1; s < 64; s <<= 1) { int x = __shfl_up(v, s); if (lane >= s) v += x; }
    if (lane == 63) wsum[w] = v;
    __syncthreads();
    if (t == 0) { int s = 0; for (int i = 0; i < 4; ++i) { int x = wsum[i]; wsum[i] = s; s += x; } }
    __syncthreads();
    int excl = wsum[w] + (v - d);
    if (t < ncnt) offs[nbase + t] = bb + excl;
    if (b == NB - 1 && t == 0) offs[NN] = NE;
    cur[t] = excl;
    __syncthreads();
    for (int i = t; i < cnt; i += 256) {
        uint32 p = gbuf[(size_t)b * CAP + i];
        int lp = atomicAdd(&cur[p >> 16], 1);
        sorted[lp] = (int)(p & 0xFFFFu);
    }
    __syncthreads();
    for (int i = t; i < cnt; i += 256)
        ssrc[bb + i] = (unsigned short)sorted[i];
}

// ---------------------------------------------------------------------------
// group-per-node fp8 gather: 16-lane group owns one node, all 128 channels
// (16 lanes x 8 fp8 = 128B row = 2 cache lines). Decode to fp16, pk_add.
// ---------------------------------------------------------------------------
__device__ inline void group_gather8(const unsigned char* __restrict__ tab,
                                     const unsigned short* __restrict__ ssrc,
                                     int s0, int deg, int md, int grp, int lig, h2* a) {
    const unsigned char* bp = tab + lig * 8;
    int idxA = (lig < deg)      ? (int)ssrc[s0 + lig]      : 0;
    int idxB = (16 + lig < deg) ? (int)ssrc[s0 + 16 + lig] : 0;
    int cap = md < 32 ? md : 32;
    for (int i0 = 0; i0 < cap; i0 += 8) {
        uint2 v[8];
        #pragma unroll
        for (int u = 0; u < 8; ++u) {
            int i = i0 + u;
            int word = (i & 16) ? idxB : idxA;
            int s = __shfl(word, grp * 16 + (i & 15));
            v[u] = *(const uint2*)(bp + (size_t)s * 128);
        }
        #pragma unroll
        for (int u = 0; u < 8; ++u) if (i0 + u < deg) ACC8Q(v[u]);
    }
    // rare tail: deg > 32
    for (int i0 = 32; i0 < md; i0 += 4) {
        uint2 v[4];
        #pragma unroll
        for (int u = 0; u < 4; ++u) {
            int i = i0 + u;
            int s = (i < deg) ? (int)ssrc[s0 + i] : 0;
            v[u] = *(const uint2*)(bp + (size_t)s * 128);
        }
        #pragma unroll
        for (int u = 0; u < 4; ++u) if (i0 + u < deg) ACC8Q(v[u]);
    }
}

// ---------------------------------------------------------------------------
// mean-aggregate fp8 x rows -> fp16 into A1 cols 0:128
// ---------------------------------------------------------------------------
__global__ void k_agg(unsigned short* __restrict__ A1, const unsigned char* __restrict__ x8,
                      const int* __restrict__ offs, const unsigned short* __restrict__ ssrc) {
    int lane = threadIdx.x & 63;
    int grp = lane >> 4, lig = lane & 15;
    int wid = (blockIdx.x * 256 + threadIdx.x) >> 6;
    int node = wid * 4 + grp;             // NN = 50000 = 12500 waves * 4, exact
    int s0 = offs[node], deg = offs[node + 1] - s0;
    int md = deg;
    md = max(md, __shfl_xor(md, 16));
    md = max(md, __shfl_xor(md, 32));
    h2 a[4] = {};
    group_gather8(x8, ssrc, s0, deg, md, grp, lig, a);
    float inv = 1.0f / fmaxf((float)deg, 1.0f);
    uint4 p;
    p.x = pack2h((float)a[0][0] * inv, (float)a[0][1] * inv);
    p.y = pack2h((float)a[1][0] * inv, (float)a[1][1] * inv);
    p.z = pack2h((float)a[2][0] * inv, (float)a[2][1] * inv);
    p.w = pack2h((float)a[3][0] * inv, (float)a[3][1] * inv);
    *(uint4*)(A1 + (size_t)node * 256 + lig * 8) = p;
}

// ---------------------------------------------------------------------------
// fp16 MFMA GEMM: [NN,256] @ [256,256], 128x128 tile, counted-vmcnt pipeline.
// SPLIT=false: C (fp16, stride 256) with optional relu+bias.
// SPLIT=true:  cols 0:128 -> p8 (fp8), cols 128:256 -> r16 (fp16).
// ---------------------------------------------------------------------------
template <bool RELU, bool SPLIT>
__global__ __launch_bounds__(256)
void k_gemm_bf(const unsigned short* __restrict__ A, const unsigned short* __restrict__ Bt,
               const float* __restrict__ bias, unsigned short* __restrict__ C,
               unsigned char* __restrict__ p8, unsigned short* __restrict__ r16) {
    __shared__ unsigned short AsmL[3][128 * 32];
    __shared__ unsigned short BsmL[3][128 * 32];
    int t = threadIdx.x;
    int lane = t & 63, w = t >> 6;
    int m0 = blockIdx.x * 128, n0 = blockIdx.y * 128;
    int wr = (w >> 1) * 64, wc = (w & 1) * 64;
    int fr = lane & 15, fk = (lane >> 4) * 8;

    f32x4 acc[4][4] = {};
    int srow = lane >> 2;
    int scol = (lane & 3) * 8;
    auto STAGE = [&](int bufi, int ks) {
        #pragma unroll
        for (int q = 0; q < 2; ++q) {
            int widx = w * 2 + q;
            int row = widx * 16 + srow;
            const unsigned short* ga = A + (size_t)(m0 + row) * 256 + ks * 32 + scol;
            __builtin_amdgcn_global_load_lds((glb_uint*)ga, (lds_uint*)&AsmL[bufi][widx * 512], 16, 0, 0);
            const unsigned short* gb = Bt + (size_t)(n0 + row) * 256 + ks * 32 + scol;
            __builtin_amdgcn_global_load_lds((glb_uint*)gb, (lds_uint*)&BsmL[bufi][widx * 512], 16, 0, 0);
        }
    };

    STAGE(0, 0);
    STAGE(1, 1);
    #pragma unroll
    for (int ks = 0; ks < 8; ++ks) {
        if (ks < 7) asm volatile("s_waitcnt vmcnt(4)" ::: "memory");
        else        asm volatile("s_waitcnt vmcnt(0)" ::: "memory");
        __builtin_amdgcn_s_barrier();
        __builtin_amdgcn_sched_barrier(0);
        if (ks < 6) STAGE((ks + 2) % 3, ks + 2);
        int cb = ks % 3;
        f16x8 af[4], bfr[4];
        #pragma unroll
        for (int i = 0; i < 4; ++i) af[i] = *(const f16x8*)&AsmL[cb][(wr + i * 16 + fr) * 32 + fk];
        #pragma unroll
        for (int j = 0; j < 4; ++j) bfr[j] = *(const f16x8*)&BsmL[cb][(wc + j * 16 + fr) * 32 + fk];
        #pragma unroll
        for (int i = 0; i < 4; ++i)
            #pragma unroll
            for (int j = 0; j < 4; ++j)
                acc[i][j] = __builtin_amdgcn_mfma_f32_16x16x32_f16(af[i], bfr[j], acc[i][j], 0, 0, 0);
    }

    int r0 = (lane >> 4) * 4;
    #pragma unroll
    for (int i = 0; i < 4; ++i) {
        #pragma unroll
        for (int j = 0; j < 4; ++j) {
            int gn = n0 + wc + j * 16 + fr;
            float bb = RELU ? bias[gn] : 0.f;
            #pragma unroll
            for (int rr = 0; rr < 4; ++rr) {
                int gm = m0 + wr + i * 16 + r0 + rr;
                if (gm >= NN) continue;
                float v = acc[i][j][rr];
                if (RELU) v = fmaxf(v + bb, 0.f);
                if (!SPLIT) {
                    C[(size_t)gm * 256 + gn] = f2h(v);
                } else {
                    if (gn < 128) p8[(size_t)gm * 128 + gn] = (unsigned char)f2e4m3(v);
                    else          r16[(size_t)gm * 128 + gn - 128] = f2h(v);
                }
            }
        }
    }
}

// ---------------------------------------------------------------------------
// out = log_softmax( mean_agg(p8) + r16 + b2 )
// ---------------------------------------------------------------------------
__global__ void k_final(const unsigned char* __restrict__ p8,
                        const unsigned short* __restrict__ r16,
                        const int* __restrict__ offs,
                        const unsigned short* __restrict__ ssrc,
                        const float* __restrict__ b2, float* __restrict__ out) {
    int lane = threadIdx.x & 63;
    int grp = lane >> 4, lig = lane & 15;
    int wid = (blockIdx.x * 256 + threadIdx.x) >> 6;
    int node = wid * 4 + grp;
    int s0 = offs[node], deg = offs[node + 1] - s0;
    int md = deg;
    md = max(md, __shfl_xor(md, 16));
    md = max(md, __shfl_xor(md, 32));
    h2 a[4] = {};
    group_gather8(p8, ssrc, s0, deg, md, grp, lig, a);
    float inv = 1.0f / fmaxf((float)deg, 1.0f);
    uint4 rv = *(const uint4*)(r16 + (size_t)node * 128 + lig * 8);
    float4 ba = *(const float4*)(b2 + lig * 8);
    float4 bb = *(const float4*)(b2 + lig * 8 + 4);
    h2 r0 = as_h2(rv.x), r1 = as_h2(rv.y), r2 = as_h2(rv.z), r3 = as_h2(rv.w);
    float vv[8];
    vv[0] = (float)a[0][0] * inv + (float)r0[0] + ba.x;
    vv[1] = (float)a[0][1] * inv + (float)r0[1] + ba.y;
    vv[2] = (float)a[1][0] * inv + (float)r1[0] + ba.z;
    vv[3] = (float)a[1][1] * inv + (float)r1[1] + ba.w;
    vv[4] = (float)a[2][0] * inv + (float)r2[0] + bb.x;
    vv[5] = (float)a[2][1] * inv + (float)r2[1] + bb.y;
    vv[6] = (float)a[3][0] * inv + (float)r3[0] + bb.z;
    vv[7] = (float)a[3][1] * inv + (float)r3[1] + bb.w;

    float mx = vv[0];
    #pragma unroll
    for (int k = 1; k < 8; ++k) mx = fmaxf(mx, vv[k]);
    #pragma unroll
    for (int d = 1; d < 16; d <<= 1) mx = fmaxf(mx, __shfl_xor(mx, d));
    float s = 0.f;
    #pragma unroll
    for (int k = 0; k < 8; ++k) s += __expf(vv[k] - mx);
    #pragma unroll
    for (int d = 1; d < 16; d <<= 1) s += __shfl_xor(s, d);
    float ls = logf(s);
    float4 o0 = make_float4(vv[0] - mx - ls, vv[1] - mx - ls, vv[2] - mx - ls, vv[3] - mx - ls);
    float4 o1 = make_float4(vv[4] - mx - ls, vv[5] - mx - ls, vv[6] - mx - ls, vv[7] - mx - ls);
    *(float4*)(out + (size_t)node * 128 + lig * 8) = o0;
    *(float4*)(out + (size_t)node * 128 + lig * 8 + 4) = o1;
}

// ---------------------------------------------------------------------------
extern "C" void kernel_launch(void* const* d_in, const int* in_sizes, int n_in,
                              void* d_out, int out_size, void* d_ws, size_t ws_size,
                              hipStream_t stream) {
    const float* x   = (const float*)d_in[0];
    const void*  edg = d_in[1];
    const float* W1l = (const float*)d_in[2];
    const float* W1r = (const float*)d_in[3];
    const float* b1  = (const float*)d_in[4];
    const float* W2l = (const float*)d_in[5];
    const float* W2r = (const float*)d_in[6];
    const float* b2  = (const float*)d_in[7];
    float* out = (float*)d_out;

    char* ws = (char*)d_ws;
    size_t off = 0;
    auto alloc = [&](size_t bytes) {
        size_t cur = off;
        off = (off + bytes + 255) & ~(size_t)255;
        return cur;
    };
    int* bcnt  = (int*)(ws + alloc((size_t)NB * 4));
    int* offs  = (int*)(ws + alloc((size_t)(NN + 1) * 4));
    unsigned short* ssrc = (unsigned short*)(ws + alloc((size_t)NE * 2));
    uint32* gbuf = (uint32*)(ws + alloc((size_t)NB * CAP * 4));                // 3.8MB
    unsigned short* A1  = (unsigned short*)(ws + alloc((size_t)NN * 256 * 2)); // [agg|x] fp16
    unsigned short* Hb  = (unsigned short*)(ws + alloc((size_t)NN * 256 * 2)); // h fp16
    unsigned char*  x8  = (unsigned char*)(ws + alloc((size_t)NN * 128));      // x fp8
    unsigned char*  p8  = (unsigned char*)(ws + alloc((size_t)NN * 128));      // p fp8
    unsigned short* r16 = (unsigned short*)(ws + alloc((size_t)NN * 128 * 2)); // r fp16
    unsigned short* B1t = (unsigned short*)(ws + alloc((size_t)65536 * 2));
    unsigned short* B2t = (unsigned short*)(ws + alloc((size_t)65536 * 2));
    // pad so gemm tail-block OOB reads stay inside ws
    (void)alloc(65536);

    int nb_g = NN / 16;                        // 3125 blocks, 16 nodes each (exact)
    int mblocks = (NN + 127) / 128;            // 391

    hipMemsetAsync(bcnt, 0, (size_t)NB * 4, stream);
    k_front<<<NBIN + NXB + NWB, 256, 0, stream>>>(edg, gbuf, bcnt, x, A1, (uint32*)x8,
                                                  W1l, W1r, W2l, W2r, B1t, B2t);
    k_sort<<<NB, 256, 0, stream>>>(gbuf, bcnt, offs, ssrc);
    // agg1 (fp8 gather) -> A1 cols 0:128
    k_agg<<<nb_g, 256, 0, stream>>>(A1, x8, offs, ssrc);
    // h = relu(A1 @ B1 + b1) -> Hb
    k_gemm_bf<true, false><<<dim3(mblocks, 2), 256, 0, stream>>>(A1, B1t, b1, Hb, nullptr, nullptr);
    // [p|r] = Hb @ B2 -> p8 (fp8) + r16 (fp16)
    k_gemm_bf<false, true><<<dim3(mblocks, 2), 256, 0, stream>>>(Hb, B2t, nullptr, nullptr, p8, r16);
    // out = log_softmax(mean_agg(p8) + r16 + b2)
    k_final<<<nb_g, 256, 0, stream>>>(p8, r16, offs, ssrc, b2, out);
}

// Round 15
// 150.031 us; speedup vs baseline: 1.0347x; 1.0347x over previous
//
#include <hip/hip_runtime.h>
#include <math.h>

#define NN 50000
#define NE 800000
#define BINW 256
#define NB ((NN + BINW - 1) / BINW)   // 196 buckets
#define CAP 4864                      // per-bucket capacity (mean 4082, sd ~64)
#define CHUNK 4096
#define NBIN ((NE + CHUNK - 1) / CHUNK)   // 196 bin blocks
#define NXB 6250                      // x-convert blocks
#define NWB 256                       // weight-convert blocks
#define EPT 16                        // edges per thread in bin phase

typedef __attribute__((ext_vector_type(8))) _Float16 f16x8;
typedef __attribute__((ext_vector_type(2))) _Float16 h2;
typedef __attribute__((ext_vector_type(4))) float f32x4;
typedef unsigned int uint32;
typedef __attribute__((address_space(3))) unsigned int lds_uint;
typedef const __attribute__((address_space(1))) unsigned int glb_uint;

__device__ inline unsigned short f2h(float f) {
    _Float16 h = (_Float16)f;        // v_cvt_f16_f32 (RNE)
    return __builtin_bit_cast(unsigned short, h);
}
__device__ inline uint32 pack2h(float a, float b) {
    return (uint32)f2h(a) | ((uint32)f2h(b) << 16);
}
__device__ inline h2 as_h2(uint32 u) { return __builtin_bit_cast(h2, u); }

// fp32 -> e4m3 byte (RNE, via fp16; denormals handled; clamp at +-448)
__device__ inline uint32 f2e4m3(float f) {
    unsigned short h = f2h(f);
    uint32 s = (h >> 8) & 0x80u;
    int E = (h >> 10) & 0x1F;
    int M = h & 0x3FF;
    if (E >= 24) return s | 0x7Eu;
    if (E > 8) {
        int m = M >> 7, r = M & 0x7F;
        if (r > 0x40 || (r == 0x40 && (m & 1))) { m++; if (m == 8) { m = 0; E++; if (E >= 24) return s | 0x7Eu; } }
        return s | (uint32)((E - 8) << 3) | (uint32)m;
    }
    if (E < 5) return s;                  // underflow -> 0
    int sh = 16 - E;                      // 8..11
    int t = 1024 + M;
    int m = t >> sh;
    int rem = t & ((1 << sh) - 1);
    int half = 1 << (sh - 1);
    if (rem > half || (rem == half && (m & 1))) m++;
    if (m >= 8) return s | 0x08u;         // rounds up to 2^-6
    return s | (uint32)m;
}

// decode 4 e4m3 bytes (one word) into two packed-fp16 words and accumulate
__device__ inline void dec_acc(uint32 w, h2* a) {
    uint32 u01 = (w & 0x7Fu) | ((w & 0x7F00u) << 8);
    uint32 u23 = ((w >> 16) & 0x7Fu) | ((w >> 8) & 0x7F0000u);
    uint32 h01 = ((u01 << 7) + 0x20002000u) | ((w & 0x80u) << 8) | ((w & 0x8000u) << 16);
    uint32 h23 = ((u23 << 7) + 0x20002000u) | ((w >> 8) & 0x8000u) | (w & 0x80000000u);
    a[0] += as_h2(h01);
    a[1] += as_h2(h23);
}
#define ACC8Q(vv) { dec_acc((vv).x, a); dec_acc((vv).y, a + 2); }

__device__ inline int edge_at(const void* edges, int is64, int i) {
    return is64 ? (int)((const long long*)edges)[i] : ((const int*)edges)[i];
}

// ---------------------------------------------------------------------------
// k_front: one launch, no cross-block deps:
// blocks [0,NBIN): bin CHUNK edges by bucket=dst>>8 -> bucket-major gbuf
// blocks [NBIN, NBIN+NXB): x fp32 -> fp16 into A1 cols 128:256 AND fp8 x8
// blocks [NBIN+NXB, ..+NWB): weights -> n-major fp16 tables
// ---------------------------------------------------------------------------
__global__ __launch_bounds__(256)
void k_front(const void* __restrict__ edges, uint32* __restrict__ gbuf,
             int* __restrict__ bcnt,
             const float* __restrict__ x, unsigned short* __restrict__ A1,
             uint32* __restrict__ x8w,
             const float* __restrict__ W1l, const float* __restrict__ W1r,
             const float* __restrict__ W2l, const float* __restrict__ W2r,
             unsigned short* __restrict__ B1t, unsigned short* __restrict__ B2t) {
    int b = blockIdx.x;
    if (b >= NBIN) {
        if (b < NBIN + NXB) {
            int t = (b - NBIN) * 256 + threadIdx.x;
            if (t >= NN * 32) return;
            int node = t >> 5, q = t & 31;
            float4 v = *(const float4*)(x + (size_t)node * 128 + q * 4);
            *(uint2*)(A1 + (size_t)node * 256 + 128 + q * 4) =
                make_uint2(pack2h(v.x, v.y), pack2h(v.z, v.w));
            x8w[(size_t)node * 32 + q] = f2e4m3(v.x) | (f2e4m3(v.y) << 8) |
                                         (f2e4m3(v.z) << 16) | (f2e4m3(v.w) << 24);
        } else {
            int t = (b - NBIN - NXB) * 256 + threadIdx.x;
            int n = t >> 8, k = t & 255;
            float v1 = (k < 128) ? W1l[k * 256 + n] : W1r[(k - 128) * 256 + n];
            B1t[n * 256 + k] = f2h(v1);
            float v2 = (n < 128) ? W2l[k * 128 + n] : W2r[k * 128 + (n - 128)];
            B2t[n * 256 + k] = f2h(v2);
        }
        return;
    }
    // ---- bin block
    __shared__ int hist[NB], excl[NB], cur[NB], gpos[NB];
    __shared__ int is64s;
    __shared__ uint32 sorted[CHUNK];
    int t = threadIdx.x;
    int base = b * CHUNK;
    int n = NE - base; if (n > CHUNK) n = CHUNK;
    if (t < 64) {
        const long long* q = (const long long*)edges;
        long long v = q[t];
        unsigned long long m = __ballot(v >= 0 && v < NN);
        if (t == 0) is64s = (m == ~0ull) ? 1 : 0;
    }
    for (int i = t; i < NB; i += 256) hist[i] = 0;
    __syncthreads();
    int is64 = is64s;
    int sA[EPT], dA[EPT];
    #pragma unroll
    for (int q = 0; q < EPT; ++q) {
        int i = t + q * 256;
        if (i < n) {
            sA[q] = edge_at(edges, is64, base + i);
            dA[q] = edge_at(edges, is64, NE + base + i);
        } else dA[q] = -1;
    }
    #pragma unroll
    for (int q = 0; q < EPT; ++q)
        if (dA[q] >= 0) atomicAdd(&hist[dA[q] >> 8], 1);
    __syncthreads();
    if (t == 0) {
        int s = 0;
        for (int k = 0; k < NB; ++k) { excl[k] = s; s += hist[k]; }
    }
    __syncthreads();
    for (int i = t; i < NB; i += 256) {
        gpos[i] = atomicAdd(&bcnt[i], hist[i]);
        cur[i] = excl[i];
    }
    __syncthreads();
    // local bucket-sort into LDS, bucket id packed in bits 24+
    #pragma unroll
    for (int q = 0; q < EPT; ++q) {
        if (dA[q] >= 0) {
            int bk = dA[q] >> 8;
            int lp = atomicAdd(&cur[bk], 1);
            sorted[lp] = ((uint32)bk << 24) | ((uint32)(dA[q] & (BINW - 1)) << 16) | (uint32)sA[q];
        }
    }
    __syncthreads();
    // coalesced-run write to bucket-major gbuf (no binary search)
    for (int i = t; i < n; i += 256) {
        uint32 v = sorted[i];
        int bk = v >> 24;
        int gp = gpos[bk] + (i - excl[bk]);
        if (gp < CAP) gbuf[(size_t)bk * CAP + gp] = v & 0xFFFFFFu;
    }
}

// ---------------------------------------------------------------------------
// k_sort: one block per bucket -> offs[] + dst-sorted src list (uint16)
// ---------------------------------------------------------------------------
__global__ __launch_bounds__(256) void k_sort(const uint32* __restrict__ gbuf,
                                              const int* __restrict__ bcnt,
                                              int* __restrict__ offs,
                                              unsigned short* __restrict__ ssrc) {
    __shared__ int hist[BINW], cur[BINW], wsum[4];
    __shared__ int sorted[CAP];
    __shared__ int bb_s;
    int b = blockIdx.x, t = threadIdx.x;
    int lane = t & 63, w = t >> 6;
    int c = (t < NB) ? bcnt[t] : 0;
    int pre = (t < b) ? c : 0;
    #pragma unroll
    for (int s = 1; s < 64; s <<= 1) pre += __shfl_xor(pre, s);
    if (lane == 0) wsum[w] = pre;
    hist[t] = 0;
    __syncthreads();
    if (t == 0) bb_s = wsum[0] + wsum[1] + wsum[2] + wsum[3];
    __syncthreads();
    int bb = bb_s;
    int cnt = bcnt[b]; if (cnt > CAP) cnt = CAP;
    int nbase = b * BINW;
    int ncnt = NN - nbase; if (ncnt > BINW) ncnt = BINW;
    for (int i = t; i < cnt; i += 256)
        atomicAdd(&hist[gbuf[(size_t)b * CAP + i] >> 16], 1);
    __syncthreads();
    int d = hist[t];
    int v = d;
    #pragma unroll
    for (int s = 1; s < 64; s <<= 1) { int x = __shfl_up(v, s); if (lane >= s) v += x; }
    if (lane == 63) wsum[w] = v;
    __syncthreads();
    if (t == 0) { int s = 0; for (int i = 0; i < 4; ++i) { int x = wsum[i]; wsum[i] = s; s += x; } }
    __syncthreads();
    int excl = wsum[w] + (v - d);
    if (t < ncnt) offs[nbase + t] = bb + excl;
    if (b == NB - 1 && t == 0) offs[NN] = NE;
    cur[t] = excl;
    __syncthreads();
    for (int i = t; i < cnt; i += 256) {
        uint32 p = gbuf[(size_t)b * CAP + i];
        int lp = atomicAdd(&cur[p >> 16], 1);
        sorted[lp] = (int)(p & 0xFFFFu);
    }
    __syncthreads();
    for (int i = t; i < cnt; i += 256)
        ssrc[bb + i] = (unsigned short)sorted[i];
}

// ---------------------------------------------------------------------------
// group-per-node fp8 gather: 16-lane group owns one node, all 128 channels
// (16 lanes x 8 fp8 = 128B row = 2 cache lines). Decode to fp16, pk_add.
// ---------------------------------------------------------------------------
__device__ inline void group_gather8(const unsigned char* __restrict__ tab,
                                     const unsigned short* __restrict__ ssrc,
                                     int s0, int deg, int md, int grp, int lig, h2* a) {
    const unsigned char* bp = tab + lig * 8;
    int idxA = (lig < deg)      ? (int)ssrc[s0 + lig]      : 0;
    int idxB = (16 + lig < deg) ? (int)ssrc[s0 + 16 + lig] : 0;
    int cap = md < 32 ? md : 32;
    for (int i0 = 0; i0 < cap; i0 += 8) {
        uint2 v[8];
        #pragma unroll
        for (int u = 0; u < 8; ++u) {
            int i = i0 + u;
            int word = (i & 16) ? idxB : idxA;
            int s = __shfl(word, grp * 16 + (i & 15));
            v[u] = *(const uint2*)(bp + (size_t)s * 128);
        }
        #pragma unroll
        for (int u = 0; u < 8; ++u) if (i0 + u < deg) ACC8Q(v[u]);
    }
    // rare tail: deg > 32
    for (int i0 = 32; i0 < md; i0 += 4) {
        uint2 v[4];
        #pragma unroll
        for (int u = 0; u < 4; ++u) {
            int i = i0 + u;
            int s = (i < deg) ? (int)ssrc[s0 + i] : 0;
            v[u] = *(const uint2*)(bp + (size_t)s * 128);
        }
        #pragma unroll
        for (int u = 0; u < 4; ++u) if (i0 + u < deg) ACC8Q(v[u]);
    }
}

// ---------------------------------------------------------------------------
// mean-aggregate fp8 x rows -> fp16 into A1 cols 0:128
// ---------------------------------------------------------------------------
__global__ void k_agg(unsigned short* __restrict__ A1, const unsigned char* __restrict__ x8,
                      const int* __restrict__ offs, const unsigned short* __restrict__ ssrc) {
    int lane = threadIdx.x & 63;
    int grp = lane >> 4, lig = lane & 15;
    int wid = (blockIdx.x * 256 + threadIdx.x) >> 6;
    int node = wid * 4 + grp;             // NN = 50000 = 12500 waves * 4, exact
    int s0 = offs[node], deg = offs[node + 1] - s0;
    int md = deg;
    md = max(md, __shfl_xor(md, 16));
    md = max(md, __shfl_xor(md, 32));
    h2 a[4] = {};
    group_gather8(x8, ssrc, s0, deg, md, grp, lig, a);
    float inv = 1.0f / fmaxf((float)deg, 1.0f);
    uint4 p;
    p.x = pack2h((float)a[0][0] * inv, (float)a[0][1] * inv);
    p.y = pack2h((float)a[1][0] * inv, (float)a[1][1] * inv);
    p.z = pack2h((float)a[2][0] * inv, (float)a[2][1] * inv);
    p.w = pack2h((float)a[3][0] * inv, (float)a[3][1] * inv);
    *(uint4*)(A1 + (size_t)node * 256 + lig * 8) = p;
}

// ---------------------------------------------------------------------------
// fp16 MFMA GEMM (exact R13 form): [NN,256] @ [256,256] -> [NN,256] fp16
// 128x128 tile, 4 waves (2x2), 4x4 frags of 16x16x32, BK=32.
// 3-buffer global_load_lds pipeline, counted vmcnt(4) + raw s_barrier.
// ---------------------------------------------------------------------------
template <bool RELU>
__global__ __launch_bounds__(256)
void k_gemm_bf(const unsigned short* __restrict__ A, const unsigned short* __restrict__ Bt,
               const float* __restrict__ bias, unsigned short* __restrict__ C) {
    __shared__ unsigned short AsmL[3][128 * 32];
    __shared__ unsigned short BsmL[3][128 * 32];
    int t = threadIdx.x;
    int lane = t & 63, w = t >> 6;
    int m0 = blockIdx.x * 128, n0 = blockIdx.y * 128;
    int wr = (w >> 1) * 64, wc = (w & 1) * 64;
    int fr = lane & 15, fk = (lane >> 4) * 8;

    f32x4 acc[4][4] = {};
    int srow = lane >> 2;
    int scol = (lane & 3) * 8;
    auto STAGE = [&](int bufi, int ks) {
        #pragma unroll
        for (int q = 0; q < 2; ++q) {
            int widx = w * 2 + q;
            int row = widx * 16 + srow;
            const unsigned short* ga = A + (size_t)(m0 + row) * 256 + ks * 32 + scol;
            __builtin_amdgcn_global_load_lds((glb_uint*)ga, (lds_uint*)&AsmL[bufi][widx * 512], 16, 0, 0);
            const unsigned short* gb = Bt + (size_t)(n0 + row) * 256 + ks * 32 + scol;
            __builtin_amdgcn_global_load_lds((glb_uint*)gb, (lds_uint*)&BsmL[bufi][widx * 512], 16, 0, 0);
        }
    };

    STAGE(0, 0);
    STAGE(1, 1);
    #pragma unroll
    for (int ks = 0; ks < 8; ++ks) {
        if (ks < 7) asm volatile("s_waitcnt vmcnt(4)" ::: "memory");
        else        asm volatile("s_waitcnt vmcnt(0)" ::: "memory");
        __builtin_amdgcn_s_barrier();
        __builtin_amdgcn_sched_barrier(0);
        if (ks < 6) STAGE((ks + 2) % 3, ks + 2);
        int cb = ks % 3;
        f16x8 af[4], bfr[4];
        #pragma unroll
        for (int i = 0; i < 4; ++i) af[i] = *(const f16x8*)&AsmL[cb][(wr + i * 16 + fr) * 32 + fk];
        #pragma unroll
        for (int j = 0; j < 4; ++j) bfr[j] = *(const f16x8*)&BsmL[cb][(wc + j * 16 + fr) * 32 + fk];
        #pragma unroll
        for (int i = 0; i < 4; ++i)
            #pragma unroll
            for (int j = 0; j < 4; ++j)
                acc[i][j] = __builtin_amdgcn_mfma_f32_16x16x32_f16(af[i], bfr[j], acc[i][j], 0, 0, 0);
    }

    int r0 = (lane >> 4) * 4;
    #pragma unroll
    for (int i = 0; i < 4; ++i) {
        #pragma unroll
        for (int j = 0; j < 4; ++j) {
            int gn = n0 + wc + j * 16 + fr;
            float bb = RELU ? bias[gn] : 0.f;
            #pragma unroll
            for (int rr = 0; rr < 4; ++rr) {
                int gm = m0 + wr + i * 16 + r0 + rr;
                if (gm >= NN) continue;
                float v = acc[i][j][rr];
                if (RELU) v = fmaxf(v + bb, 0.f);
                C[(size_t)gm * 256 + gn] = f2h(v);
            }
        }
    }
}

// ---------------------------------------------------------------------------
// k_cvt8: Pb cols 0:128 (fp16) -> p8 (e4m3), fully coalesced
// ---------------------------------------------------------------------------
__global__ void k_cvt8(const unsigned short* __restrict__ Pb, uint2* __restrict__ p8w) {
    int t = blockIdx.x * 256 + threadIdx.x;
    if (t >= NN * 16) return;
    int node = t >> 4, lig = t & 15;
    uint4 v = *(const uint4*)(Pb + (size_t)node * 256 + lig * 8);
    h2 h0 = as_h2(v.x), h1 = as_h2(v.y), hzw0 = as_h2(v.z), hzw1 = as_h2(v.w);
    uint32 w0 = f2e4m3((float)h0[0]) | (f2e4m3((float)h0[1]) << 8) |
                (f2e4m3((float)h1[0]) << 16) | (f2e4m3((float)h1[1]) << 24);
    uint32 w1 = f2e4m3((float)hzw0[0]) | (f2e4m3((float)hzw0[1]) << 8) |
                (f2e4m3((float)hzw1[0]) << 16) | (f2e4m3((float)hzw1[1]) << 24);
    p8w[t] = make_uint2(w0, w1);
}

// ---------------------------------------------------------------------------
// out = log_softmax( mean_agg(p8) + r + b2 ); r = Pb cols 128:256
// ---------------------------------------------------------------------------
__global__ void k_final(const unsigned char* __restrict__ p8,
                        const unsigned short* __restrict__ Pb,
                        const int* __restrict__ offs,
                        const unsigned short* __restrict__ ssrc,
                        const float* __restrict__ b2, float* __restrict__ out) {
    int lane = threadIdx.x & 63;
    int grp = lane >> 4, lig = lane & 15;
    int wid = (blockIdx.x * 256 + threadIdx.x) >> 6;
    int node = wid * 4 + grp;
    int s0 = offs[node], deg = offs[node + 1] - s0;
    int md = deg;
    md = max(md, __shfl_xor(md, 16));
    md = max(md, __shfl_xor(md, 32));
    h2 a[4] = {};
    group_gather8(p8, ssrc, s0, deg, md, grp, lig, a);
    float inv = 1.0f / fmaxf((float)deg, 1.0f);
    uint4 rv = *(const uint4*)(Pb + (size_t)node * 256 + 128 + lig * 8);
    float4 ba = *(const float4*)(b2 + lig * 8);
    float4 bb = *(const float4*)(b2 + lig * 8 + 4);
    h2 r0 = as_h2(rv.x), r1 = as_h2(rv.y), r2 = as_h2(rv.z), r3 = as_h2(rv.w);
    float vv[8];
    vv[0] = (float)a[0][0] * inv + (float)r0[0] + ba.x;
    vv[1] = (float)a[0][1] * inv + (float)r0[1] + ba.y;
    vv[2] = (float)a[1][0] * inv + (float)r1[0] + ba.z;
    vv[3] = (float)a[1][1] * inv + (float)r1[1] + ba.w;
    vv[4] = (float)a[2][0] * inv + (float)r2[0] + bb.x;
    vv[5] = (float)a[2][1] * inv + (float)r2[1] + bb.y;
    vv[6] = (float)a[3][0] * inv + (float)r3[0] + bb.z;
    vv[7] = (float)a[3][1] * inv + (float)r3[1] + bb.w;

    float mx = vv[0];
    #pragma unroll
    for (int k = 1; k < 8; ++k) mx = fmaxf(mx, vv[k]);
    #pragma unroll
    for (int d = 1; d < 16; d <<= 1) mx = fmaxf(mx, __shfl_xor(mx, d));
    float s = 0.f;
    #pragma unroll
    for (int k = 0; k < 8; ++k) s += __expf(vv[k] - mx);
    #pragma unroll
    for (int d = 1; d < 16; d <<= 1) s += __shfl_xor(s, d);
    float ls = logf(s);
    float4 o0 = make_float4(vv[0] - mx - ls, vv[1] - mx - ls, vv[2] - mx - ls, vv[3] - mx - ls);
    float4 o1 = make_float4(vv[4] - mx - ls, vv[5] - mx - ls, vv[6] - mx - ls, vv[7] - mx - ls);
    *(float4*)(out + (size_t)node * 128 + lig * 8) = o0;
    *(float4*)(out + (size_t)node * 128 + lig * 8 + 4) = o1;
}

// ---------------------------------------------------------------------------
extern "C" void kernel_launch(void* const* d_in, const int* in_sizes, int n_in,
                              void* d_out, int out_size, void* d_ws, size_t ws_size,
                              hipStream_t stream) {
    const float* x   = (const float*)d_in[0];
    const void*  edg = d_in[1];
    const float* W1l = (const float*)d_in[2];
    const float* W1r = (const float*)d_in[3];
    const float* b1  = (const float*)d_in[4];
    const float* W2l = (const float*)d_in[5];
    const float* W2r = (const float*)d_in[6];
    const float* b2  = (const float*)d_in[7];
    float* out = (float*)d_out;

    char* ws = (char*)d_ws;
    size_t off = 0;
    auto alloc = [&](size_t bytes) {
        size_t cur = off;
        off = (off + bytes + 255) & ~(size_t)255;
        return cur;
    };
    int* bcnt  = (int*)(ws + alloc((size_t)NB * 4));
    int* offs  = (int*)(ws + alloc((size_t)(NN + 1) * 4));
    unsigned short* ssrc = (unsigned short*)(ws + alloc((size_t)NE * 2));
    uint32* gbuf = (uint32*)(ws + alloc((size_t)NB * CAP * 4));                // 3.8MB
    unsigned short* A1  = (unsigned short*)(ws + alloc((size_t)NN * 256 * 2)); // [agg|x] fp16
    unsigned short* Hb  = (unsigned short*)(ws + alloc((size_t)NN * 256 * 2)); // h fp16
    unsigned short* Pb  = (unsigned short*)(ws + alloc((size_t)NN * 256 * 2)); // [p|r] fp16
    unsigned char*  x8  = (unsigned char*)(ws + alloc((size_t)NN * 128));      // x fp8
    unsigned char*  p8  = (unsigned char*)(ws + alloc((size_t)NN * 128));      // p fp8
    unsigned short* B1t = (unsigned short*)(ws + alloc((size_t)65536 * 2));
    unsigned short* B2t = (unsigned short*)(ws + alloc((size_t)65536 * 2));
    // pad so gemm tail-block OOB reads stay inside ws
    (void)alloc(65536);

    int nb_g = NN / 16;                        // 3125 blocks, 16 nodes each (exact)
    int mblocks = (NN + 127) / 128;            // 391

    hipMemsetAsync(bcnt, 0, (size_t)NB * 4, stream);
    k_front<<<NBIN + NXB + NWB, 256, 0, stream>>>(edg, gbuf, bcnt, x, A1, (uint32*)x8,
                                                  W1l, W1r, W2l, W2r, B1t, B2t);
    k_sort<<<NB, 256, 0, stream>>>(gbuf, bcnt, offs, ssrc);
    // agg1 (fp8 gather) -> A1 cols 0:128
    k_agg<<<nb_g, 256, 0, stream>>>(A1, x8, offs, ssrc);
    // h = relu(A1 @ B1 + b1) -> Hb
    k_gemm_bf<true><<<dim3(mblocks, 2), 256, 0, stream>>>(A1, B1t, b1, Hb);
    // [p|r] = Hb @ B2 -> Pb
    k_gemm_bf<false><<<dim3(mblocks, 2), 256, 0, stream>>>(Hb, B2t, nullptr, Pb);
    // p -> fp8 (coalesced)
    k_cvt8<<<nb_g, 256, 0, stream>>>(Pb, (uint2*)p8);
    // out = log_softmax(mean_agg(p8) + r + b2)
    k_final<<<nb_g, 256, 0, stream>>>(p8, Pb, offs, ssrc, b2, out);
}

// Round 16
// 136.951 us; speedup vs baseline: 1.1335x; 1.0955x over previous
//
#include <hip/hip_runtime.h>
#include <math.h>

#define NN 50000
#define NE 800000
#define BINW 256
#define NB ((NN + BINW - 1) / BINW)   // 196 buckets
#define CAP 4864                      // per-bucket capacity (mean 4082, sd ~64)
#define CHUNK 4096
#define NBIN ((NE + CHUNK - 1) / CHUNK)   // 196 bin blocks
#define NXB 6250                      // x-convert blocks
#define NWB 256                       // weight-convert blocks
#define EPT 16                        // edges per thread in bin phase

typedef __attribute__((ext_vector_type(8))) _Float16 f16x8;
typedef __attribute__((ext_vector_type(2))) _Float16 h2;
typedef __attribute__((ext_vector_type(4))) float f32x4;
typedef unsigned int uint32;
typedef __attribute__((address_space(3))) unsigned int lds_uint;
typedef const __attribute__((address_space(1))) unsigned int glb_uint;

__device__ inline unsigned short f2h(float f) {
    _Float16 h = (_Float16)f;        // v_cvt_f16_f32 (RNE)
    return __builtin_bit_cast(unsigned short, h);
}
__device__ inline uint32 pack2h(float a, float b) {
    return (uint32)f2h(a) | ((uint32)f2h(b) << 16);
}
__device__ inline h2 as_h2(uint32 u) { return __builtin_bit_cast(h2, u); }

__device__ inline int edge_at(const void* edges, int is64, int i) {
    return is64 ? (int)((const long long*)edges)[i] : ((const int*)edges)[i];
}

// ---------------------------------------------------------------------------
// k_front: one launch, no cross-block deps:
// blocks [0,NBIN): bin CHUNK edges by bucket=dst>>8; reserve global space via
//   atomicAdd(bcnt) and write bucket-major runs to gbuf[b*CAP + gpos..]
//   packed word: bk<<24 | dloc<<16 | src  (bk<=195, dloc<256, src<50000)
// blocks [NBIN, NBIN+NXB): x fp32 -> fp16 into A1 cols 128:256
// blocks [NBIN+NXB, ..+NWB): weights -> n-major fp16 tables
// ---------------------------------------------------------------------------
__global__ __launch_bounds__(256)
void k_front(const void* __restrict__ edges, uint32* __restrict__ gbuf,
             int* __restrict__ bcnt,
             const float* __restrict__ x, unsigned short* __restrict__ A1,
             const float* __restrict__ W1l, const float* __restrict__ W1r,
             const float* __restrict__ W2l, const float* __restrict__ W2r,
             unsigned short* __restrict__ B1t, unsigned short* __restrict__ B2t) {
    int b = blockIdx.x;
    if (b >= NBIN) {
        if (b < NBIN + NXB) {
            int t = (b - NBIN) * 256 + threadIdx.x;
            if (t >= NN * 32) return;
            int node = t >> 5, q = t & 31;
            float4 v = *(const float4*)(x + (size_t)node * 128 + q * 4);
            *(uint2*)(A1 + (size_t)node * 256 + 128 + q * 4) =
                make_uint2(pack2h(v.x, v.y), pack2h(v.z, v.w));
        } else {
            int t = (b - NBIN - NXB) * 256 + threadIdx.x;
            int n = t >> 8, k = t & 255;
            float v1 = (k < 128) ? W1l[k * 256 + n] : W1r[(k - 128) * 256 + n];
            B1t[n * 256 + k] = f2h(v1);
            float v2 = (n < 128) ? W2l[k * 128 + n] : W2r[k * 128 + (n - 128)];
            B2t[n * 256 + k] = f2h(v2);
        }
        return;
    }
    // ---- bin block
    __shared__ int hist[NB], excl[NB], cur[NB], gpos[NB];
    __shared__ int is64s;
    __shared__ uint32 sorted[CHUNK];
    int t = threadIdx.x;
    int base = b * CHUNK;
    int n = NE - base; if (n > CHUNK) n = CHUNK;
    if (t < 64) {
        const long long* q = (const long long*)edges;
        long long v = q[t];
        unsigned long long m = __ballot(v >= 0 && v < NN);
        if (t == 0) is64s = (m == ~0ull) ? 1 : 0;
    }
    for (int i = t; i < NB; i += 256) hist[i] = 0;
    __syncthreads();
    int is64 = is64s;
    int sA[EPT], dA[EPT];
    #pragma unroll
    for (int q = 0; q < EPT; ++q) {
        int i = t + q * 256;
        if (i < n) {
            sA[q] = edge_at(edges, is64, base + i);
            dA[q] = edge_at(edges, is64, NE + base + i);
        } else dA[q] = -1;
    }
    #pragma unroll
    for (int q = 0; q < EPT; ++q)
        if (dA[q] >= 0) atomicAdd(&hist[dA[q] >> 8], 1);
    __syncthreads();
    if (t == 0) {
        int s = 0;
        for (int k = 0; k < NB; ++k) { excl[k] = s; s += hist[k]; }
    }
    __syncthreads();
    for (int i = t; i < NB; i += 256) {
        gpos[i] = atomicAdd(&bcnt[i], hist[i]);
        cur[i] = excl[i];
    }
    __syncthreads();
    // local bucket-sort into LDS, bucket id packed in bits 24+
    #pragma unroll
    for (int q = 0; q < EPT; ++q) {
        if (dA[q] >= 0) {
            int bk = dA[q] >> 8;
            int lp = atomicAdd(&cur[bk], 1);
            sorted[lp] = ((uint32)bk << 24) | ((uint32)(dA[q] & (BINW - 1)) << 16) | (uint32)sA[q];
        }
    }
    __syncthreads();
    // coalesced-run write to bucket-major gbuf: bucket id read directly from
    // the packed word -> two independent LDS lookups, no binary search.
    for (int i = t; i < n; i += 256) {
        uint32 v = sorted[i];
        int bk = v >> 24;
        int gp = gpos[bk] + (i - excl[bk]);
        if (gp < CAP) gbuf[(size_t)bk * CAP + gp] = v & 0xFFFFFFu;
    }
}

// ---------------------------------------------------------------------------
// k_sort: one block per bucket. Computes its own bucket base (reduce over
// bcnt[0..b)), reads its contiguous gbuf segment, LDS counting-sort by local
// node, emits offs[] + dst-sorted src list (uint16).
// ---------------------------------------------------------------------------
__global__ __launch_bounds__(256) void k_sort(const uint32* __restrict__ gbuf,
                                              const int* __restrict__ bcnt,
                                              int* __restrict__ offs,
                                              unsigned short* __restrict__ ssrc) {
    __shared__ int hist[BINW], cur[BINW], wsum[4];
    __shared__ int sorted[CAP];
    __shared__ int bb_s;
    int b = blockIdx.x, t = threadIdx.x;
    int lane = t & 63, w = t >> 6;
    // bucket base = sum_{k<b} bcnt[k]  (one coalesced load + block reduce)
    int c = (t < NB) ? bcnt[t] : 0;
    int pre = (t < b) ? c : 0;
    #pragma unroll
    for (int s = 1; s < 64; s <<= 1) pre += __shfl_xor(pre, s);
    if (lane == 0) wsum[w] = pre;
    hist[t] = 0;
    __syncthreads();
    if (t == 0) bb_s = wsum[0] + wsum[1] + wsum[2] + wsum[3];
    __syncthreads();
    int bb = bb_s;
    int cnt = bcnt[b]; if (cnt > CAP) cnt = CAP;
    int nbase = b * BINW;
    int ncnt = NN - nbase; if (ncnt > BINW) ncnt = BINW;
    for (int i = t; i < cnt; i += 256)
        atomicAdd(&hist[gbuf[(size_t)b * CAP + i] >> 16], 1);
    __syncthreads();
    // exclusive scan of 256 counters (1/thread)
    int d = hist[t];
    int v = d;
    #pragma unroll
    for (int s = 1; s < 64; s <<= 1) { int x = __shfl_up(v, s); if (lane >= s) v += x; }
    if (lane == 63) wsum[w] = v;
    __syncthreads();
    if (t == 0) { int s = 0; for (int i = 0; i < 4; ++i) { int x = wsum[i]; wsum[i] = s; s += x; } }
    __syncthreads();
    int excl = wsum[w] + (v - d);
    if (t < ncnt) offs[nbase + t] = bb + excl;
    if (b == NB - 1 && t == 0) offs[NN] = NE;   // counts always sum to NE
    cur[t] = excl;
    __syncthreads();
    // counting-sort scatter in LDS
    for (int i = t; i < cnt; i += 256) {
        uint32 p = gbuf[(size_t)b * CAP + i];
        int lp = atomicAdd(&cur[p >> 16], 1);
        sorted[lp] = (int)(p & 0xFFFFu);
    }
    __syncthreads();
    // coalesced output
    for (int i = t; i < cnt; i += 256)
        ssrc[bb + i] = (unsigned short)sorted[i];
}

// ---------------------------------------------------------------------------
// group-per-node gather: each 16-lane group owns ONE node and holds all 128
// channels (16 lanes x 8 fp16). 4 nodes/wave. Indices preloaded per group;
// batched-8 row loads (one row per group per wave-VMEM-op); packed h2 accum;
// no cross-lane reduce needed.
// ---------------------------------------------------------------------------
#define ACCH1(vv) { a[0] += as_h2((vv).x); a[1] += as_h2((vv).y); \
                    a[2] += as_h2((vv).z); a[3] += as_h2((vv).w); }

__device__ inline void group_gather(const unsigned short* __restrict__ tab, int coff,
                                    const unsigned short* __restrict__ ssrc,
                                    int s0, int deg, int md, int grp, int lig, h2* a) {
    const unsigned short* bp = tab + coff + lig * 8;
    int idxA = (lig < deg)      ? (int)ssrc[s0 + lig]      : 0;
    int idxB = (16 + lig < deg) ? (int)ssrc[s0 + 16 + lig] : 0;
    int cap = md < 32 ? md : 32;
    for (int i0 = 0; i0 < cap; i0 += 8) {
        uint4 v[8];
        #pragma unroll
        for (int u = 0; u < 8; ++u) {
            int i = i0 + u;
            int word = (i & 16) ? idxB : idxA;
            int s = __shfl(word, grp * 16 + (i & 15));
            v[u] = *(const uint4*)(bp + (size_t)s * 256);
        }
        #pragma unroll
        for (int u = 0; u < 8; ++u) if (i0 + u < deg) ACCH1(v[u]);
    }
    // rare tail: deg > 32
    for (int i0 = 32; i0 < md; i0 += 4) {
        uint4 v[4];
        #pragma unroll
        for (int u = 0; u < 4; ++u) {
            int i = i0 + u;
            int s = (i < deg) ? (int)ssrc[s0 + i] : 0;   // group-uniform addr
            v[u] = *(const uint4*)(bp + (size_t)s * 256);
        }
        #pragma unroll
        for (int u = 0; u < 4; ++u) if (i0 + u < deg) ACCH1(v[u]);
    }
}

// ---------------------------------------------------------------------------
// mean-aggregate fp16 rows (A1 cols 128:256) -> fp16 (A1 cols 0:128)
// ---------------------------------------------------------------------------
__global__ void k_agg(unsigned short* __restrict__ A1, const int* __restrict__ offs,
                      const unsigned short* __restrict__ ssrc) {
    int lane = threadIdx.x & 63;
    int grp = lane >> 4, lig = lane & 15;
    int wid = (blockIdx.x * 256 + threadIdx.x) >> 6;
    int node = wid * 4 + grp;             // NN = 50000 = 12500 waves * 4, exact
    int s0 = offs[node], deg = offs[node + 1] - s0;
    int md = deg;
    md = max(md, __shfl_xor(md, 16));
    md = max(md, __shfl_xor(md, 32));
    h2 a[4] = {};
    group_gather(A1, 128, ssrc, s0, deg, md, grp, lig, a);
    float inv = 1.0f / fmaxf((float)deg, 1.0f);
    uint4 p;
    p.x = pack2h((float)a[0][0] * inv, (float)a[0][1] * inv);
    p.y = pack2h((float)a[1][0] * inv, (float)a[1][1] * inv);
    p.z = pack2h((float)a[2][0] * inv, (float)a[2][1] * inv);
    p.w = pack2h((float)a[3][0] * inv, (float)a[3][1] * inv);
    *(uint4*)(A1 + (size_t)node * 256 + lig * 8) = p;
}

// ---------------------------------------------------------------------------
// fp16 MFMA GEMM: [NN,256] @ [256,256] -> [NN,256] fp16
// 128x128 tile, 4 waves (2x2), 4x4 frags of 16x16x32, BK=32.
// 3-buffer global_load_lds pipeline, 2 K-steps prefetched, counted vmcnt(4)
// + raw s_barrier (loads stay in flight across barriers; drain only at tail).
// ---------------------------------------------------------------------------
template <bool RELU>
__global__ __launch_bounds__(256)
void k_gemm_bf(const unsigned short* __restrict__ A, const unsigned short* __restrict__ Bt,
               const float* __restrict__ bias, unsigned short* __restrict__ C) {
    __shared__ unsigned short AsmL[3][128 * 32];
    __shared__ unsigned short BsmL[3][128 * 32];
    int t = threadIdx.x;
    int lane = t & 63, w = t >> 6;
    int m0 = blockIdx.x * 128, n0 = blockIdx.y * 128;
    int wr = (w >> 1) * 64, wc = (w & 1) * 64;
    int fr = lane & 15, fk = (lane >> 4) * 8;

    f32x4 acc[4][4] = {};
    int srow = lane >> 2;            // 0..15 within the 16-row stripe
    int scol = (lane & 3) * 8;       // ushort offset of this lane's 16B
    auto STAGE = [&](int bufi, int ks) {
        #pragma unroll
        for (int q = 0; q < 2; ++q) {
            int widx = w * 2 + q;
            int row = widx * 16 + srow;
            const unsigned short* ga = A + (size_t)(m0 + row) * 256 + ks * 32 + scol;
            __builtin_amdgcn_global_load_lds((glb_uint*)ga, (lds_uint*)&AsmL[bufi][widx * 512], 16, 0, 0);
            const unsigned short* gb = Bt + (size_t)(n0 + row) * 256 + ks * 32 + scol;
            __builtin_amdgcn_global_load_lds((glb_uint*)gb, (lds_uint*)&BsmL[bufi][widx * 512], 16, 0, 0);
        }
    };

    STAGE(0, 0);
    STAGE(1, 1);
    #pragma unroll
    for (int ks = 0; ks < 8; ++ks) {
        if (ks < 7) asm volatile("s_waitcnt vmcnt(4)" ::: "memory");
        else        asm volatile("s_waitcnt vmcnt(0)" ::: "memory");
        __builtin_amdgcn_s_barrier();
        __builtin_amdgcn_sched_barrier(0);
        if (ks < 6) STAGE((ks + 2) % 3, ks + 2);   // issue 2-ahead, stays in flight
        int cb = ks % 3;
        f16x8 af[4], bfr[4];
        #pragma unroll
        for (int i = 0; i < 4; ++i) af[i] = *(const f16x8*)&AsmL[cb][(wr + i * 16 + fr) * 32 + fk];
        #pragma unroll
        for (int j = 0; j < 4; ++j) bfr[j] = *(const f16x8*)&BsmL[cb][(wc + j * 16 + fr) * 32 + fk];
        #pragma unroll
        for (int i = 0; i < 4; ++i)
            #pragma unroll
            for (int j = 0; j < 4; ++j)
                acc[i][j] = __builtin_amdgcn_mfma_f32_16x16x32_f16(af[i], bfr[j], acc[i][j], 0, 0, 0);
    }

    int r0 = (lane >> 4) * 4;
    #pragma unroll
    for (int i = 0; i < 4; ++i) {
        #pragma unroll
        for (int j = 0; j < 4; ++j) {
            int gn = n0 + wc + j * 16 + fr;
            float bb = RELU ? bias[gn] : 0.f;
            #pragma unroll
            for (int rr = 0; rr < 4; ++rr) {
                int gm = m0 + wr + i * 16 + r0 + rr;
                if (gm >= NN) continue;
                float v = acc[i][j][rr];
                if (RELU) v = fmaxf(v + bb, 0.f);
                C[(size_t)gm * 256 + gn] = f2h(v);
            }
        }
    }
}

// ---------------------------------------------------------------------------
// out = log_softmax( mean_agg(p) + r + b2 ); p = P cols 0:128, r = cols 128:256
// group-per-node: 16-lane group owns one node; softmax reduce within group.
// ---------------------------------------------------------------------------
__global__ void k_final(const unsigned short* __restrict__ P, const int* __restrict__ offs,
                        const unsigned short* __restrict__ ssrc, const float* __restrict__ b2,
                        float* __restrict__ out) {
    int lane = threadIdx.x & 63;
    int grp = lane >> 4, lig = lane & 15;
    int wid = (blockIdx.x * 256 + threadIdx.x) >> 6;
    int node = wid * 4 + grp;
    int s0 = offs[node], deg = offs[node + 1] - s0;
    int md = deg;
    md = max(md, __shfl_xor(md, 16));
    md = max(md, __shfl_xor(md, 32));
    h2 a[4] = {};
    group_gather(P, 0, ssrc, s0, deg, md, grp, lig, a);
    float inv = 1.0f / fmaxf((float)deg, 1.0f);
    uint4 rv = *(const uint4*)(P + (size_t)node * 256 + 128 + lig * 8);
    float4 ba = *(const float4*)(b2 + lig * 8);
    float4 bb = *(const float4*)(b2 + lig * 8 + 4);
    h2 r0 = as_h2(rv.x), r1 = as_h2(rv.y), r2 = as_h2(rv.z), r3 = as_h2(rv.w);
    float vv[8];
    vv[0] = (float)a[0][0] * inv + (float)r0[0] + ba.x;
    vv[1] = (float)a[0][1] * inv + (float)r0[1] + ba.y;
    vv[2] = (float)a[1][0] * inv + (float)r1[0] + ba.z;
    vv[3] = (float)a[1][1] * inv + (float)r1[1] + ba.w;
    vv[4] = (float)a[2][0] * inv + (float)r2[0] + bb.x;
    vv[5] = (float)a[2][1] * inv + (float)r2[1] + bb.y;
    vv[6] = (float)a[3][0] * inv + (float)r3[0] + bb.z;
    vv[7] = (float)a[3][1] * inv + (float)r3[1] + bb.w;

    float mx = vv[0];
    #pragma unroll
    for (int k = 1; k < 8; ++k) mx = fmaxf(mx, vv[k]);
    #pragma unroll
    for (int d = 1; d < 16; d <<= 1) mx = fmaxf(mx, __shfl_xor(mx, d));
    float s = 0.f;
    #pragma unroll
    for (int k = 0; k < 8; ++k) s += __expf(vv[k] - mx);
    #pragma unroll
    for (int d = 1; d < 16; d <<= 1) s += __shfl_xor(s, d);
    float ls = logf(s);
    float4 o0 = make_float4(vv[0] - mx - ls, vv[1] - mx - ls, vv[2] - mx - ls, vv[3] - mx - ls);
    float4 o1 = make_float4(vv[4] - mx - ls, vv[5] - mx - ls, vv[6] - mx - ls, vv[7] - mx - ls);
    *(float4*)(out + (size_t)node * 128 + lig * 8) = o0;
    *(float4*)(out + (size_t)node * 128 + lig * 8 + 4) = o1;
}

// ---------------------------------------------------------------------------
extern "C" void kernel_launch(void* const* d_in, const int* in_sizes, int n_in,
                              void* d_out, int out_size, void* d_ws, size_t ws_size,
                              hipStream_t stream) {
    const float* x   = (const float*)d_in[0];
    const void*  edg = d_in[1];
    const float* W1l = (const float*)d_in[2];
    const float* W1r = (const float*)d_in[3];
    const float* b1  = (const float*)d_in[4];
    const float* W2l = (const float*)d_in[5];
    const float* W2r = (const float*)d_in[6];
    const float* b2  = (const float*)d_in[7];
    float* out = (float*)d_out;

    char* ws = (char*)d_ws;
    size_t off = 0;
    auto alloc = [&](size_t bytes) {
        size_t cur = off;
        off = (off + bytes + 255) & ~(size_t)255;
        return cur;
    };
    int* bcnt  = (int*)(ws + alloc((size_t)NB * 4));
    int* offs  = (int*)(ws + alloc((size_t)(NN + 1) * 4));
    unsigned short* ssrc = (unsigned short*)(ws + alloc((size_t)NE * 2));
    uint32* gbuf = (uint32*)(ws + alloc((size_t)NB * CAP * 4));              // 3.8MB
    unsigned short* A1  = (unsigned short*)(ws + alloc((size_t)NN * 256 * 2)); // [agg|x] fp16
    unsigned short* Hb  = (unsigned short*)(ws + alloc((size_t)NN * 256 * 2)); // h fp16
    unsigned short* Pb  = (unsigned short*)(ws + alloc((size_t)NN * 256 * 2)); // [p|r] fp16
    unsigned short* B1t = (unsigned short*)(ws + alloc((size_t)65536 * 2));
    unsigned short* B2t = (unsigned short*)(ws + alloc((size_t)65536 * 2));
    // pad so gemm tail-block OOB reads stay inside ws
    (void)alloc(65536);

    int nb_g = NN / 16;                        // 3125 blocks, 16 nodes each (exact)
    int mblocks = (NN + 127) / 128;            // 391

    hipMemsetAsync(bcnt, 0, (size_t)NB * 4, stream);
    k_front<<<NBIN + NXB + NWB, 256, 0, stream>>>(edg, gbuf, bcnt, x, A1,
                                                  W1l, W1r, W2l, W2r, B1t, B2t);
    k_sort<<<NB, 256, 0, stream>>>(gbuf, bcnt, offs, ssrc);
    // agg1 -> A1 cols 0:128
    k_agg<<<nb_g, 256, 0, stream>>>(A1, offs, ssrc);
    // h = relu(A1 @ B1 + b1) -> Hb
    k_gemm_bf<true><<<dim3(mblocks, 2), 256, 0, stream>>>(A1, B1t, b1, Hb);
    // [p|r] = Hb @ B2 -> Pb
    k_gemm_bf<false><<<dim3(mblocks, 2), 256, 0, stream>>>(Hb, B2t, nullptr, Pb);
    // out = log_softmax(mean_agg(p) + r + b2)
    k_final<<<nb_g, 256, 0, stream>>>(Pb, offs, ssrc, b2, out);
}